// Round 5
// baseline (487.345 us; speedup 1.0000x reference)
//
#include <hip/hip_runtime.h>

#define D_MAX 2048
#define EPSF 1e-6f
#define E5F 148.4131591f   // e^5
#define BLK 512
#define GRID 1024

// LDS per-date u64 layout (low->high):  stp:24 @2^4 | pden:24 @2^10 | n0:8 | n1:8
// Global per-date u64 layout (low->high): n0:12 | n1:12 | pden:18 @2^4 | stp:22 @2^1
// R10: MAX-MLP + MERGED FINALIZE. R9 decomposition found the law: effective BW ~
// 0.4 TB/s per in-flight 16B load/thread (volk 4->1.07, fusedk 6->2.5, dirk 8->3.3
// TB/s), linear, nothing saturated. Every prior round self-capped MLP via
// __launch_bounds__(...,8) => 64-VGPR cap => allocator serialized loads (VGPR stuck
// at 24-32 despite unrolls). This round: launch_bounds(512,4) (VGPR cap 128,
// 16 waves/CU) + fully-unrolled x4 grid-stride = 24 loads (96 data VGPRs) issued
// back-to-back before sched_barrier(0). Also merges finalk in via last-block-done
// (device-scope atomics + threadfence, no spin => dispatch-order safe): 3 launches
// -> 2. Lever check: VGPR ~100-128. Predict megak 48-58us, total ~175.

__global__ void initk(unsigned long long* g_pd, double* sum_q, unsigned* n_valid,
                      unsigned* done, const int* ndp) {
    int i = blockIdx.x * blockDim.x + threadIdx.x;
    int nd = ndp[0]; if (nd > D_MAX) nd = D_MAX;
    if (i == 0) { *sum_q = 0.0; *n_valid = 0u; *done = 0u; }
    if (i < nd) g_pd[i] = 0ULL;
}

__device__ __forceinline__ void volElem(float p, float tg, double& accq, unsigned& accn) {
    if (tg > EPSF && p > EPSF) {   // NaN tgt fails compare, matching ~isnan & >eps
        float pv = fmaxf(p * p, EPSF);
        float tv = fmaxf(tg * tg, EPSF);
        accq += (double)(__fdividef(tv, pv) + __logf(pv));
        accn++;
    }
}

__device__ __forceinline__ void volGroup(const float4& p4, const float4& t4,
                                         double& accq, unsigned& accn) {
    volElem(p4.x, t4.x, accq, accn);
    volElem(p4.y, t4.y, accq, accn);
    volElem(p4.z, t4.z, accq, accn);
    volElem(p4.w, t4.w, accq, accn);
}

__device__ __forceinline__ void dirElem(int lb, int d, float l0, float l1,
                                        unsigned long long* s_pack) {
    if (lb >= 0) {
        // p1 = softmax(logits)[:,1]; segment-max shift cancels exactly in the ratios
        float p1 = __fdividef(1.0f, 1.0f + __expf(l0 - l1));
        float pe = __expf(p1);                 // in (1, e): no overflow
        float w  = (lb >= 1) ? E5F * p1 : p1;  // te * p1, te in {1, e^5}
        unsigned stp_i = (unsigned)(w * 16.0f + 0.5f);
        unsigned pd_i  = (unsigned)(pe * 1024.0f + 0.5f);
        unsigned long long inc = (unsigned long long)stp_i
                               | ((unsigned long long)pd_i << 24)
                               | (1ULL << (48 + 8 * (lb >= 1)));
        atomicAdd(&s_pack[d], inc);
    }
}

__device__ __forceinline__ void dirGroup(const int4& l4, const int4& d4,
                                         const float4& ga, const float4& gb,
                                         unsigned long long* s_pack) {
    dirElem(l4.x, d4.x, ga.x, ga.y, s_pack);
    dirElem(l4.y, d4.y, ga.z, ga.w, s_pack);
    dirElem(l4.z, d4.z, gb.x, gb.y, s_pack);
    dirElem(l4.w, d4.w, gb.z, gb.w, s_pack);
}

__global__ __launch_bounds__(BLK, 4)   // 4 waves/EU min -> VGPR cap 128, 2 blocks/CU
void megak(const float4* __restrict__ lg4, const int4* __restrict__ lab4,
           const float4* __restrict__ vp4, const float4* __restrict__ vt4,
           const int4* __restrict__ dt4, int B,
           unsigned long long* __restrict__ g_pd,
           double* __restrict__ sum_q, unsigned* __restrict__ n_valid,
           unsigned* __restrict__ done, const int* __restrict__ ndp,
           float* __restrict__ out) {
    __shared__ unsigned long long s_pack[D_MAX];
    __shared__ double s_q[BLK / 64];
    __shared__ unsigned s_n[BLK / 64];
    __shared__ unsigned s_last;
    int nd = ndp[0]; if (nd > D_MAX) nd = D_MAX;
    int B4 = B >> 2;

    for (int d = threadIdx.x; d < nd; d += BLK) s_pack[d] = 0ULL;
    __syncthreads();

    const int stride = GRID * BLK;
    int tid = blockIdx.x * BLK + threadIdx.x;
    double accq = 0.0;
    unsigned accn = 0u;

    int n = B4 / stride;   // = 4 at B=8.4M: the x4-unrolled body runs exactly once
    int k = 0;
    // ---- 24 x 16B loads issued back-to-back (96 data VGPRs), then consume ----
    for (; k + 4 <= n; k += 4) {
        int i0 = tid + k * stride, i1 = i0 + stride, i2 = i1 + stride, i3 = i2 + stride;
        float4 pv0 = vp4[i0], pv1 = vp4[i1], pv2 = vp4[i2], pv3 = vp4[i3];
        float4 tv0 = vt4[i0], tv1 = vt4[i1], tv2 = vt4[i2], tv3 = vt4[i3];
        int4   la0 = lab4[i0], la1 = lab4[i1], la2 = lab4[i2], la3 = lab4[i3];
        int4   da0 = dt4[i0],  da1 = dt4[i1],  da2 = dt4[i2],  da3 = dt4[i3];
        float4 ga0 = lg4[2 * i0], ga1 = lg4[2 * i1], ga2 = lg4[2 * i2], ga3 = lg4[2 * i3];
        float4 gb0 = lg4[2 * i0 + 1], gb1 = lg4[2 * i1 + 1],
               gb2 = lg4[2 * i2 + 1], gb3 = lg4[2 * i3 + 1];
        __builtin_amdgcn_sched_barrier(0);   // all 24 loads stay above, uses below
        volGroup(pv0, tv0, accq, accn);
        volGroup(pv1, tv1, accq, accn);
        volGroup(pv2, tv2, accq, accn);
        volGroup(pv3, tv3, accq, accn);
        dirGroup(la0, da0, ga0, gb0, s_pack);
        dirGroup(la1, da1, ga1, gb1, s_pack);
        dirGroup(la2, da2, ga2, gb2, s_pack);
        dirGroup(la3, da3, ga3, gb3, s_pack);
    }
    for (; k < n; k++) {
        int i = tid + k * stride;
        volGroup(vp4[i], vt4[i], accq, accn);
        dirGroup(lab4[i], dt4[i], lg4[2 * i], lg4[2 * i + 1], s_pack);
    }
    // leftover grid-stride elements (B4 % stride) + scalar tail (B % 4)
    for (int i = tid + n * stride; i < B4; i += stride) {
        volGroup(vp4[i], vt4[i], accq, accn);
        dirGroup(lab4[i], dt4[i], lg4[2 * i], lg4[2 * i + 1], s_pack);
    }
    int rem = B & 3;
    if (tid < rem) {
        int j = (B4 << 2) + tid;
        volElem(((const float*)vp4)[j], ((const float*)vt4)[j], accq, accn);
        dirElem(((const int*)lab4)[j], ((const int*)dt4)[j],
                ((const float*)lg4)[2 * j], ((const float*)lg4)[2 * j + 1], s_pack);
    }

    // ---- vol reduce: wave shuffle -> LDS across waves -> one atomic pair/block ----
    for (int o = 32; o > 0; o >>= 1) {
        accq += __shfl_down(accq, o);
        accn += __shfl_down(accn, o);
    }
    int lane = threadIdx.x & 63, wv = threadIdx.x >> 6;
    if (lane == 0) { s_q[wv] = accq; s_n[wv] = accn; }
    __syncthreads();   // also drains all s_pack LDS atomics before the flush below
    if (threadIdx.x == 0) {
        double q = 0.0; unsigned nn = 0u;
        for (int w = 0; w < BLK / 64; w++) { q += s_q[w]; nn += s_n[w]; }
        atomicAdd(sum_q, q);
        atomicAdd(n_valid, nn);
    }

    // ---- dir flush: ONE packed u64 global atomic per nonzero date, staggered ----
    int start = (blockIdx.x & 7) * BLK;
    if (start >= nd) start %= nd;
    for (int kk = 0; kk < (nd + BLK - 1) / BLK; kk++) {
        int d0 = threadIdx.x + kk * BLK;
        if (d0 < nd) {
            int d = d0 + start;
            if (d >= nd) d -= nd;
            unsigned long long c = s_pack[d];
            if (c) {
                unsigned stp24 = (unsigned)(c & 0xFFFFFFu);          // @2^4
                unsigned pd24  = (unsigned)((c >> 24) & 0xFFFFFFu);  // @2^10
                unsigned n0 = (unsigned)((c >> 48) & 0xFFu);
                unsigned n1 = (unsigned)(c >> 56);
                unsigned pd4  = (pd24 + 32u) >> 6;   // -> @2^4
                unsigned stp1 = (stp24 + 4u) >> 3;   // -> @2^1
                unsigned long long ginc = (unsigned long long)n0
                                        | ((unsigned long long)n1 << 12)
                                        | ((unsigned long long)pd4 << 24)
                                        | ((unsigned long long)stp1 << 42);
                atomicAdd(&g_pd[d], ginc);
            }
        }
    }

    // ---- merged finalize: last block to FINISH does it (no spin, order-safe) ----
    __threadfence();                    // release: flush + sum_q visible before 'done'
    __syncthreads();                    // all threads of this block done flushing
    if (threadIdx.x == 0) s_last = atomicAdd(done, 1u);
    __syncthreads();
    if (s_last == (unsigned)(gridDim.x - 1)) {
        __threadfence();                // acquire side
        double ce = 0.0; unsigned cnt = 0u;
        for (int d = threadIdx.x; d < nd; d += BLK) {
            unsigned long long pk = atomicAdd(&g_pd[d], 0ULL);   // device-scope read
            unsigned n0 = (unsigned)(pk & 0xFFFu);
            unsigned n1 = (unsigned)((pk >> 12) & 0xFFFu);
            if (n0 + n1 >= 2u) {
                float pden = (float)((pk >> 24) & 0x3FFFFu) * (1.0f / 16.0f);
                float stp  = (float)(pk >> 42) * 0.5f;
                float td   = (float)n0 + (float)n1 * E5F;
                ce += (double)(__logf(fmaxf(pden, 1e-30f)) - stp / td);
                cnt++;
            }
        }
        for (int o = 32; o > 0; o >>= 1) { ce += __shfl_down(ce, o); cnt += __shfl_down(cnt, o); }
        if (lane == 0) { s_q[wv] = ce; s_n[wv] = cnt; }
        __syncthreads();
        if (threadIdx.x == 0) {
            double dce = 0.0; unsigned ncnt = 0u;
            for (int w = 0; w < BLK / 64; w++) { dce += s_q[w]; ncnt += s_n[w]; }
            double sq = atomicAdd(sum_q, 0.0);                    // device-scope read
            unsigned nv = atomicAdd(n_valid, 0u);
            double vol = nv ? sq / (double)nv : 0.0;
            double dir = dce / (double)(ncnt ? ncnt : 1u);
            out[0] = (float)(0.85 * vol + 0.15 * dir);
            out[1] = (float)vol;
            out[2] = (float)dir;
        }
    }
}

extern "C" void kernel_launch(void* const* d_in, const int* in_sizes, int n_in,
                              void* d_out, int out_size, void* d_ws, size_t ws_size,
                              hipStream_t stream) {
    const float4* lg4 = (const float4*)d_in[0];
    const int4* lab4  = (const int4*)d_in[1];
    const float4* vp4 = (const float4*)d_in[2];
    const float4* vt4 = (const float4*)d_in[3];
    const int4* dt4   = (const int4*)d_in[4];
    const int* ndp    = (const int*)d_in[5];
    int B = in_sizes[1];
    float* out = (float*)d_out;

    char* ws = (char*)d_ws;
    double*   sum_q   = (double*)(ws + 0);
    unsigned* n_valid = (unsigned*)(ws + 8);
    unsigned* done    = (unsigned*)(ws + 12);
    unsigned long long* g_pd = (unsigned long long*)(ws + 64);  // 16 KB

    initk<<<(D_MAX + 255) / 256, 256, 0, stream>>>(g_pd, sum_q, n_valid, done, ndp);
    megak<<<GRID, BLK, 0, stream>>>(lg4, lab4, vp4, vt4, dt4, B,
                                    g_pd, sum_q, n_valid, done, ndp, out);
}

// Round 6
// 210.016 us; speedup vs baseline: 2.3205x; 2.3205x over previous
//
#include <hip/hip_runtime.h>

#define D_MAX 2048
#define EPSF 1e-6f
#define E5F 148.4131591f   // e^5
#define BLK 512
#define GRID 1024

// LDS per-date u64 layout (low->high):  stp:24 @2^4 | pden:24 @2^10 | n0:8 | n1:8
// Global per-date u64 layout (low->high): n0:12 | n1:12 | pden:18 @2^4 | stp:22 @2^1
// R11: INLINE-ASM DEPTH-2 LOAD PIPELINE. Evidence: every compiler-scheduled variant
// (R5-R10) emitted load-serialized inner loops (VGPR 16-56) regardless of source
// unroll/sched_barrier; kernels are only ~2-4 dependent memory epochs deep and the
// wall fits epochs x queued-latency (invariant to L3 residency, flush, schedule).
// volk (no LDS, no atomics) at 1 TB/s killed the DS-atomic theory; megak (16
// waves/CU + sched_barrier(0)) at 374us killed low-TLP + order-pinning. This round
// forces ISA-level MLP: raw global_load_dwordx4 into two 24-VGPR banks, counted
// s_waitcnt vmcnt(6) that TIES payload registers (consume can't hoist above it),
// 12 loads/thread always in flight, launch_bounds(512,6) (cap 85, 24 waves/CU).
// Math byte-identical to R6 -> absmax 0.0. Lever check: VGPR 64-85.

typedef float f4 __attribute__((ext_vector_type(4)));
typedef int   i4 __attribute__((ext_vector_type(4)));

// Raw 16B global load, no wait: issue and move on.
#define GL4(dst, p) asm volatile("global_load_dwordx4 %0, %1, off" \
                                 : "=v"(dst) : "v"((const void*)(p)))

// Counted waits that tie one bank's 6 payload vectors: uses of these values are
// data-dependent on the waitcnt asm, so the compiler cannot schedule consumes
// before the hardware wait (rule #18 analog, done via dependence not clobbers).
#define WAITBANK6(pv, tv, la, da, ga, gb)                        \
    asm volatile("s_waitcnt vmcnt(6)"                            \
                 : "+v"(pv), "+v"(tv), "+v"(la), "+v"(da), "+v"(ga), "+v"(gb))
#define WAITBANK0(pv, tv, la, da, ga, gb)                        \
    asm volatile("s_waitcnt vmcnt(0)"                            \
                 : "+v"(pv), "+v"(tv), "+v"(la), "+v"(da), "+v"(ga), "+v"(gb))

#define ISSUE6(pv, tv, la, da, ga, gb, i)   \
    do { int _i = (i);                      \
        GL4(pv, vp4 + _i);                  \
        GL4(tv, vt4 + _i);                  \
        GL4(la, lab4 + _i);                 \
        GL4(da, dt4 + _i);                  \
        GL4(ga, lg4 + 2 * _i);              \
        GL4(gb, lg4 + 2 * _i + 1);          \
    } while (0)

__global__ void initk(unsigned long long* g_pd, double* sum_q, unsigned* n_valid,
                      const int* ndp) {
    int i = blockIdx.x * blockDim.x + threadIdx.x;
    int nd = ndp[0]; if (nd > D_MAX) nd = D_MAX;
    if (i == 0) { *sum_q = 0.0; *n_valid = 0u; }
    if (i < nd) g_pd[i] = 0ULL;
}

__device__ __forceinline__ void volElem(float p, float tg, double& accq, unsigned& accn) {
    if (tg > EPSF && p > EPSF) {   // NaN tgt fails compare, matching ~isnan & >eps
        float pv = fmaxf(p * p, EPSF);
        float tv = fmaxf(tg * tg, EPSF);
        accq += (double)(__fdividef(tv, pv) + __logf(pv));
        accn++;
    }
}

__device__ __forceinline__ void dirElem(int lb, int d, float l0, float l1,
                                        unsigned long long* s_pack) {
    if (lb >= 0) {
        // p1 = softmax(logits)[:,1]; segment-max shift cancels exactly in the ratios
        float p1 = __fdividef(1.0f, 1.0f + __expf(l0 - l1));
        float pe = __expf(p1);                 // in (1, e): no overflow
        float w  = (lb >= 1) ? E5F * p1 : p1;  // te * p1, te in {1, e^5}
        unsigned stp_i = (unsigned)(w * 16.0f + 0.5f);
        unsigned pd_i  = (unsigned)(pe * 1024.0f + 0.5f);
        unsigned long long inc = (unsigned long long)stp_i
                               | ((unsigned long long)pd_i << 24)
                               | (1ULL << (48 + 8 * (lb >= 1)));
        atomicAdd(&s_pack[d], inc);
    }
}

__device__ __forceinline__ void consume6(const f4& pv, const f4& tv,
                                         const i4& la, const i4& da,
                                         const f4& ga, const f4& gb,
                                         double& accq, unsigned& accn,
                                         unsigned long long* s_pack) {
    volElem(pv.x, tv.x, accq, accn);
    volElem(pv.y, tv.y, accq, accn);
    volElem(pv.z, tv.z, accq, accn);
    volElem(pv.w, tv.w, accq, accn);
    dirElem(la.x, da.x, ga.x, ga.y, s_pack);
    dirElem(la.y, da.y, ga.z, ga.w, s_pack);
    dirElem(la.z, da.z, gb.x, gb.y, s_pack);
    dirElem(la.w, da.w, gb.z, gb.w, s_pack);
}

__global__ __launch_bounds__(BLK, 6)   // VGPR cap ~85; 3 blocks/CU = 24 waves/CU
void fusedk(const f4* __restrict__ lg4, const i4* __restrict__ lab4,
            const f4* __restrict__ vp4, const f4* __restrict__ vt4,
            const i4* __restrict__ dt4, int B,
            unsigned long long* __restrict__ g_pd,
            double* __restrict__ sum_q, unsigned* __restrict__ n_valid,
            const int* __restrict__ ndp) {
    __shared__ unsigned long long s_pack[D_MAX];
    __shared__ double s_q[BLK / 64];
    __shared__ unsigned s_n[BLK / 64];
    int nd = ndp[0]; if (nd > D_MAX) nd = D_MAX;
    int B4 = B >> 2;

    for (int d = threadIdx.x; d < nd; d += BLK) s_pack[d] = 0ULL;
    __syncthreads();

    const int stride = GRID * BLK;
    int tid = blockIdx.x * BLK + threadIdx.x;
    double accq = 0.0;
    unsigned accn = 0u;

    int n = B4 / stride;       // = 4 at B = 8.4M
    int npair = n & ~1;        // pipeline handles an even number of rounds
    int kdone = 0;

    if (npair >= 2) {
        f4 pvA, tvA, gaA, gbA; i4 laA, daA;
        f4 pvB, tvB, gaB, gbB; i4 laB, daB;
        // prologue: 12 loads in flight
        ISSUE6(pvA, tvA, laA, daA, gaA, gbA, tid);
        ISSUE6(pvB, tvB, laB, daB, gaB, gbB, tid + stride);
        int k = 0;
        for (; k + 2 < npair; k += 2) {
            WAITBANK6(pvA, tvA, laA, daA, gaA, gbA);   // oldest 6 (bank A) done
            consume6(pvA, tvA, laA, daA, gaA, gbA, accq, accn, s_pack);
            ISSUE6(pvA, tvA, laA, daA, gaA, gbA, tid + (k + 2) * stride);
            WAITBANK6(pvB, tvB, laB, daB, gaB, gbB);
            consume6(pvB, tvB, laB, daB, gaB, gbB, accq, accn, s_pack);
            ISSUE6(pvB, tvB, laB, daB, gaB, gbB, tid + (k + 3) * stride);
        }
        WAITBANK6(pvA, tvA, laA, daA, gaA, gbA);       // B's 6 still outstanding
        consume6(pvA, tvA, laA, daA, gaA, gbA, accq, accn, s_pack);
        WAITBANK0(pvB, tvB, laB, daB, gaB, gbB);       // drain
        consume6(pvB, tvB, laB, daB, gaB, gbB, accq, accn, s_pack);
        kdone = npair;
    }
    // leftover rounds (n odd and/or B4 % stride) via plain compiler-scheduled loads
    for (int i = tid + kdone * stride; i < B4; i += stride) {
        f4 pv = vp4[i], tv = vt4[i];
        i4 la = lab4[i], da = dt4[i];
        f4 ga = lg4[2 * i], gb = lg4[2 * i + 1];
        consume6(pv, tv, la, da, ga, gb, accq, accn, s_pack);
    }
    // scalar tail (B % 4)
    int rem = B & 3;
    if (tid < rem) {
        int j = (B4 << 2) + tid;
        volElem(((const float*)vp4)[j], ((const float*)vt4)[j], accq, accn);
        dirElem(((const int*)lab4)[j], ((const int*)dt4)[j],
                ((const float*)lg4)[2 * j], ((const float*)lg4)[2 * j + 1], s_pack);
    }

    // ---- vol reduce: wave shuffle -> LDS across waves -> one atomic pair/block ----
    for (int o = 32; o > 0; o >>= 1) {
        accq += __shfl_down(accq, o);
        accn += __shfl_down(accn, o);
    }
    int lane = threadIdx.x & 63, wv = threadIdx.x >> 6;
    if (lane == 0) { s_q[wv] = accq; s_n[wv] = accn; }
    __syncthreads();   // also drains all s_pack LDS atomics before the flush below
    if (threadIdx.x == 0) {
        double q = 0.0; unsigned nn = 0u;
        for (int w = 0; w < BLK / 64; w++) { q += s_q[w]; nn += s_n[w]; }
        atomicAdd(sum_q, q);
        atomicAdd(n_valid, nn);
    }

    // ---- dir flush: ONE packed u64 global atomic per nonzero date, staggered ----
    int start = (blockIdx.x & 7) * BLK;
    if (start >= nd) start %= nd;
    for (int kk = 0; kk < (nd + BLK - 1) / BLK; kk++) {
        int d0 = threadIdx.x + kk * BLK;
        if (d0 < nd) {
            int d = d0 + start;
            if (d >= nd) d -= nd;
            unsigned long long c = s_pack[d];
            if (c) {
                unsigned stp24 = (unsigned)(c & 0xFFFFFFu);          // @2^4
                unsigned pd24  = (unsigned)((c >> 24) & 0xFFFFFFu);  // @2^10
                unsigned n0 = (unsigned)((c >> 48) & 0xFFu);
                unsigned n1 = (unsigned)(c >> 56);
                unsigned pd4  = (pd24 + 32u) >> 6;   // -> @2^4
                unsigned stp1 = (stp24 + 4u) >> 3;   // -> @2^1
                unsigned long long ginc = (unsigned long long)n0
                                        | ((unsigned long long)n1 << 12)
                                        | ((unsigned long long)pd4 << 24)
                                        | ((unsigned long long)stp1 << 42);
                atomicAdd(&g_pd[d], ginc);
            }
        }
    }
}

__global__ void finalk(const unsigned long long* __restrict__ g_pd, const int* __restrict__ ndp,
                       const double* __restrict__ sum_q, const unsigned* __restrict__ n_valid,
                       float* __restrict__ out) {
    __shared__ double s_ce[4];
    __shared__ unsigned s_c[4];
    int nd = ndp[0]; if (nd > D_MAX) nd = D_MAX;
    double ce = 0.0; unsigned cnt = 0u;
    for (int d = threadIdx.x; d < nd; d += 256) {
        unsigned long long pk = g_pd[d];
        unsigned n0 = (unsigned)(pk & 0xFFFu);
        unsigned n1 = (unsigned)((pk >> 12) & 0xFFFu);
        if (n0 + n1 >= 2u) {
            float pden = (float)((pk >> 24) & 0x3FFFFu) * (1.0f / 16.0f);
            float stp  = (float)(pk >> 42) * 0.5f;
            float td   = (float)n0 + (float)n1 * E5F;
            ce += (double)(__logf(fmaxf(pden, 1e-30f)) - stp / td);
            cnt++;
        }
    }
    for (int o = 32; o > 0; o >>= 1) { ce += __shfl_down(ce, o); cnt += __shfl_down(cnt, o); }
    int lane = threadIdx.x & 63, w = threadIdx.x >> 6;
    if (lane == 0) { s_ce[w] = ce; s_c[w] = cnt; }
    __syncthreads();
    if (threadIdx.x == 0) {
        double dce = s_ce[0] + s_ce[1] + s_ce[2] + s_ce[3];
        unsigned n = s_c[0] + s_c[1] + s_c[2] + s_c[3];
        unsigned nv = *n_valid;
        double vol = nv ? (*sum_q) / (double)nv : 0.0;
        double dir = dce / (double)(n ? n : 1u);
        out[0] = (float)(0.85 * vol + 0.15 * dir);
        out[1] = (float)vol;
        out[2] = (float)dir;
    }
}

extern "C" void kernel_launch(void* const* d_in, const int* in_sizes, int n_in,
                              void* d_out, int out_size, void* d_ws, size_t ws_size,
                              hipStream_t stream) {
    const f4* lg4 = (const f4*)d_in[0];
    const i4* lab4 = (const i4*)d_in[1];
    const f4* vp4 = (const f4*)d_in[2];
    const f4* vt4 = (const f4*)d_in[3];
    const i4* dt4 = (const i4*)d_in[4];
    const int* ndp = (const int*)d_in[5];
    int B = in_sizes[1];
    float* out = (float*)d_out;

    char* ws = (char*)d_ws;
    double*   sum_q   = (double*)(ws + 0);
    unsigned* n_valid = (unsigned*)(ws + 8);
    unsigned long long* g_pd = (unsigned long long*)(ws + 64);  // 16 KB

    initk<<<(D_MAX + 255) / 256, 256, 0, stream>>>(g_pd, sum_q, n_valid, ndp);
    fusedk<<<GRID, BLK, 0, stream>>>(lg4, lab4, vp4, vt4, dt4, B,
                                     g_pd, sum_q, n_valid, ndp);
    finalk<<<1, 256, 0, stream>>>(g_pd, ndp, sum_q, n_valid, out);
}